// Round 18
// baseline (259.862 us; speedup 1.0000x reference)
//
#include <hip/hip_runtime.h>
#include <hip/hip_bf16.h>
#include <math.h>

#define EMBED 1024
#define NHEADS 16
#define HDIM 64
#define BATCH 4
#define SQL 1024
#define SKL 2048
#define PSC 0.18033688f   // 0.125 * log2(e)  (folded into Q projection)

typedef unsigned short u16;
typedef __attribute__((ext_vector_type(4))) float f32x4;
typedef __attribute__((ext_vector_type(8))) __bf16 bf16x8;
typedef __attribute__((ext_vector_type(8))) short s16x8;
typedef __attribute__((ext_vector_type(4))) short s16x4;
typedef __attribute__((ext_vector_type(8))) u16 u16x8;
typedef __attribute__((ext_vector_type(2))) unsigned u32x2;

__device__ __forceinline__ u16 f2bf(float x) {
    __hip_bfloat16 h = __float2bfloat16(x);
    return *reinterpret_cast<u16*>(&h);
}
__device__ __forceinline__ float bf2f(u16 u) {
    __hip_bfloat16 h;
    *reinterpret_cast<u16*>(&h) = u;
    return __bfloat162float(h);
}
// Truncation-pack: {bf16_trunc(e1), bf16_trunc(e0)} in one v_perm_b32.
__device__ __forceinline__ unsigned permpack(float e0, float e1) {
    return __builtin_amdgcn_perm(__builtin_bit_cast(unsigned, e1),
                                 __builtin_bit_cast(unsigned, e0), 0x07060302u);
}
__device__ __forceinline__ f32x4 mfma16(s16x8 a, s16x8 b, f32x4 c) {
    return __builtin_amdgcn_mfma_f32_16x16x32_bf16(
        __builtin_bit_cast(bf16x8, a), __builtin_bit_cast(bf16x8, b), c, 0, 0, 0);
}
__device__ __forceinline__ f32x4 mfma16k16(s16x4 a, s16x4 b, f32x4 c) {
    return __builtin_amdgcn_mfma_f32_16x16x16bf16_1k(a, b, c, 0, 0, 0);
}
__device__ __forceinline__ void gload16(const void* g, void* l) {
    __builtin_amdgcn_global_load_lds(
        (const __attribute__((address_space(1))) void*)g,
        (__attribute__((address_space(3))) void*)l, 16, 0, 0);
}
// Stage one 8KB plane (64 rows x 128B) with XOR-preswizzled source.
__device__ __forceinline__ void stage8k(const char* g, size_t rstrideB,
                                        char* ldsPlane, int w, int lane) {
    int r = w * 8 + (lane >> 3);
    int cs = (lane & 7) ^ (r & 7);
    gload16(g + (size_t)r * rstrideB + cs * 16, ldsPlane + (size_t)w * 1024);
}
#define SBAR() { __builtin_amdgcn_sched_barrier(0); \
    __builtin_amdgcn_s_barrier(); __builtin_amdgcn_sched_barrier(0); }

// ---------------------------------------------------------------------------
// cvt_w: all four weight matrices f32 -> bf16 (hi only, RNE).
// ---------------------------------------------------------------------------
__global__ __launch_bounds__(256)
void cvt_w(const float* __restrict__ Wq, const float* __restrict__ Wk,
           const float* __restrict__ Wv, const float* __restrict__ Wo,
           u16* __restrict__ Wqh, u16* __restrict__ Wkh,
           u16* __restrict__ Wvh, u16* __restrict__ Woh) {
    int bid = blockIdx.x;
    const float* src; u16* dh;
    if (bid < 512)       { src = Wq; dh = Wqh; }
    else if (bid < 1024) { bid -= 512;  src = Wk; dh = Wkh; }
    else if (bid < 1536) { bid -= 1024; src = Wv; dh = Wvh; }
    else                 { bid -= 1536; src = Wo; dh = Woh; }
    size_t i = ((size_t)bid * 256 + threadIdx.x) * 8;
    float4 a = *(const float4*)&src[i];
    float4 b = *(const float4*)&src[i + 4];
    float v[8] = {a.x, a.y, a.z, a.w, b.x, b.y, b.z, b.w};
    u16x8 hi;
#pragma unroll
    for (int j = 0; j < 8; ++j) hi[j] = f2bf(v[j]);
    *(u16x8*)&dh[i] = hi;
}

// ---------------------------------------------------------------------------
// Fused Q/K/V projection GEMM: one launch, 1280 blocks (5/CU), role per block.
//  role 0 (blocks [0,256)):   Qhi = query @ Wqh^T * PSC + bq   (OUT head-major, bshift 10)
//  role 1 (blocks [256,768)): Khi = key @ Wkh^T + bk           (OUT head-major, bshift 11)
//  role 2 (blocks [768,1280)): VTh = (Wvh @ value^T + bv[row]) (OUT V^T head-major)
// Same 128x128 tile / BK=32 / 2-deep register prefetch as the proven template;
// bf16-side loads overlay the f32 staging arrays (no extra registers).
// ---------------------------------------------------------------------------
#define QKV_FLOAD(dst, base, row, kk) { \
    _Pragma("unroll") for (int j = 0; j < 4; ++j) \
        *(float4*)&dst[j * 4] = *(const float4*)((base) + (((size_t)(row) * 1024 + (kk) + sc + j * 4) << 2)); }
#define QKV_BLOAD(dst, base, row, kk) { \
    *(u16x8*)&dst[0] = *(const u16x8*)((base) + (((size_t)(row) * 1024 + (kk) + sc) << 1)); \
    *(u16x8*)&dst[4] = *(const u16x8*)((base) + (((size_t)(row) * 1024 + (kk) + sc + 8) << 1)); }

#define QKV_LOAD(S, kk) { \
    if (af32) { QKV_FLOAD(ax##S, Abase, rowBase + srow, kk) } \
    else      { QKV_BLOAD(ax##S, Abase, rowBase + srow, kk) } \
    if (wf32) { QKV_FLOAD(bx##S, Wbase, colBase + srow, kk) } \
    else      { QKV_BLOAD(bx##S, Wbase, colBase + srow, kk) } }

#define QKV_WRITE(S) { \
    u16x8 h0, h1; \
    if (af32) { \
        _Pragma("unroll") for (int j = 0; j < 8; ++j) { \
            h0[j] = f2bf(ax##S[j]); h1[j] = f2bf(ax##S[j + 8]); } \
    } else { h0 = *(u16x8*)&ax##S[0]; h1 = *(u16x8*)&ax##S[4]; } \
    *(u16x8*)&sA[srow * 40 + sc] = h0; \
    *(u16x8*)&sA[srow * 40 + sc + 8] = h1; \
    u16x8 b0, b1; \
    if (wf32) { \
        _Pragma("unroll") for (int j = 0; j < 8; ++j) { \
            b0[j] = f2bf(bx##S[j]); b1[j] = f2bf(bx##S[j + 8]); } \
    } else { b0 = *(u16x8*)&bx##S[0]; b1 = *(u16x8*)&bx##S[4]; } \
    *(u16x8*)&sB[srow * 40 + sc] = b0; \
    *(u16x8*)&sB[srow * 40 + sc + 8] = b1; }

#define QKV_COMPUTE() { \
    s16x8 afh[4], bfh[4]; \
    _Pragma("unroll") for (int mi = 0; mi < 4; ++mi) { \
        int ai = (wm * 64 + mi * 16 + (lane & 15)) * 40 + (lane >> 4) * 8; \
        afh[mi] = *(const s16x8*)&sA[ai]; \
    } \
    _Pragma("unroll") for (int ni = 0; ni < 4; ++ni) { \
        int bi = (wn * 64 + ni * 16 + (lane & 15)) * 40 + (lane >> 4) * 8; \
        bfh[ni] = *(const s16x8*)&sB[bi]; \
    } \
    _Pragma("unroll") for (int mi = 0; mi < 4; ++mi) \
        _Pragma("unroll") for (int ni = 0; ni < 4; ++ni) \
            acc[mi][ni] = mfma16(afh[mi], bfh[ni], acc[mi][ni]); }

__global__ __launch_bounds__(256)
void gemm_qkv(const float* __restrict__ query, const float* __restrict__ key,
              const float* __restrict__ value,
              const u16* __restrict__ Wqh, const u16* __restrict__ Wkh,
              const u16* __restrict__ Wvh,
              const float* __restrict__ bq, const float* __restrict__ bk,
              const float* __restrict__ bv,
              u16* __restrict__ Qhi, u16* __restrict__ Khi, u16* __restrict__ VTh) {
    __shared__ u16 sA[128 * 40];
    __shared__ u16 sB[128 * 40];

    const int t = threadIdx.x;
    const int lane = t & 63;
    const int w = t >> 6;
    const int wm = w >> 1, wn = w & 1;
    const int srow = t >> 1;
    const int sc = (t & 1) * 16;

    int bid = blockIdx.x;
    int role, bx, by;
    if (bid < 256)      { role = 0; bx = bid & 7; by = bid >> 3; }
    else if (bid < 768) { role = 1; int r = bid - 256; bx = r & 7; by = r >> 3; }
    else                { role = 2; int r = bid - 768; bx = r & 63; by = r >> 6; }
    const int rowBase = by * 128;
    const int colBase = bx * 128;
    const bool af32 = (role != 2);
    const bool wf32 = (role == 2);
    const char* Abase = (role == 0) ? (const char*)query
                      : (role == 1) ? (const char*)key
                                    : (const char*)Wvh;
    const char* Wbase = (role == 0) ? (const char*)Wqh
                      : (role == 1) ? (const char*)Wkh
                                    : (const char*)value;

    f32x4 acc[4][4];
#pragma unroll
    for (int i = 0; i < 4; ++i)
#pragma unroll
        for (int j = 0; j < 4; ++j) acc[i][j] = (f32x4){0.f, 0.f, 0.f, 0.f};

    float ax0[16], ax1[16], bx0[16], bx1[16];

    QKV_LOAD(0, 0)
    QKV_LOAD(1, 32)

    for (int k0 = 0; k0 < 1024; k0 += 64) {
        __syncthreads();
        QKV_WRITE(0)
        __syncthreads();
        if (k0 + 64 < 1024) QKV_LOAD(0, k0 + 64)
        QKV_COMPUTE()
        __syncthreads();
        QKV_WRITE(1)
        __syncthreads();
        if (k0 + 96 < 1024) QKV_LOAD(1, k0 + 96)
        QKV_COMPUTE()
    }

#pragma unroll
    for (int mi = 0; mi < 4; ++mi)
#pragma unroll
        for (int ni = 0; ni < 4; ++ni)
#pragma unroll
            for (int rr = 0; rr < 4; ++rr) {
                int mg = rowBase + wm * 64 + mi * 16 + (lane >> 4) * 4 + rr;
                int ng = colBase + wn * 64 + ni * 16 + (lane & 15);
                float y = acc[mi][ni][rr];
                if (role == 2) {
                    y += bv[mg];
                    size_t idx = ((size_t)((ng >> 11) * 16 + (mg >> 6)) * 64 + (mg & 63)) * 2048 + (ng & 2047);
                    VTh[idx] = f2bf(y);
                } else if (role == 0) {
                    y = (y + bq[ng]) * PSC;
                    int bb = mg >> 10, s = mg & 1023;
                    size_t idx = ((((size_t)(bb * 16 + (ng >> 6))) << 10) + s) * 64 + (ng & 63);
                    Qhi[idx] = f2bf(y);
                } else {
                    y += bk[ng];
                    int bb = mg >> 11, s = mg & 2047;
                    size_t idx = ((((size_t)(bb * 16 + (ng >> 6))) << 11) + s) * 64 + (ng & 63);
                    Khi[idx] = f2bf(y);
                }
            }
}

// ---------------------------------------------------------------------------
// O-projection GEMM (unchanged r17 template, single instantiation):
// out = Att @ Woh^T + bo, f32 output.
// ---------------------------------------------------------------------------
__global__ __launch_bounds__(256)
void gemm_oproj(const u16* __restrict__ Au, const u16* __restrict__ Wu,
                const float* __restrict__ bias, float* __restrict__ Y0p) {
    __shared__ u16 sA[128 * 40];
    __shared__ u16 sB[128 * 40];

    const int t = threadIdx.x;
    const int lane = t & 63;
    const int w = t >> 6;
    const int wm = w >> 1, wn = w & 1;
    const int rowBase = blockIdx.y * 128;
    const int colBase = blockIdx.x * 128;
    const int srow = t >> 1;
    const int sc = (t & 1) * 16;

    f32x4 acc[4][4];
#pragma unroll
    for (int i = 0; i < 4; ++i)
#pragma unroll
        for (int j = 0; j < 4; ++j) acc[i][j] = (f32x4){0.f, 0.f, 0.f, 0.f};

    u16x8 au00, au01, au10, au11;
    u16x8 wh00, wh01, wh10, wh11;

#define OP_LOAD(S, kk) { \
    au##S##0 = *(const u16x8*)&Au[(size_t)(rowBase + srow) * 1024 + (kk) + sc]; \
    au##S##1 = *(const u16x8*)&Au[(size_t)(rowBase + srow) * 1024 + (kk) + sc + 8]; \
    wh##S##0 = *(const u16x8*)&Wu[(size_t)(colBase + srow) * 1024 + (kk) + sc]; \
    wh##S##1 = *(const u16x8*)&Wu[(size_t)(colBase + srow) * 1024 + (kk) + sc + 8]; }
#define OP_WRITE(S) { \
    *(u16x8*)&sA[srow * 40 + sc] = au##S##0; \
    *(u16x8*)&sA[srow * 40 + sc + 8] = au##S##1; \
    *(u16x8*)&sB[srow * 40 + sc] = wh##S##0; \
    *(u16x8*)&sB[srow * 40 + sc + 8] = wh##S##1; }

    OP_LOAD(0, 0)
    OP_LOAD(1, 32)

    for (int k0 = 0; k0 < 1024; k0 += 64) {
        __syncthreads();
        OP_WRITE(0)
        __syncthreads();
        if (k0 + 64 < 1024) OP_LOAD(0, k0 + 64)
        QKV_COMPUTE()
        __syncthreads();
        OP_WRITE(1)
        __syncthreads();
        if (k0 + 96 < 1024) OP_LOAD(1, k0 + 96)
        QKV_COMPUTE()
    }

#pragma unroll
    for (int mi = 0; mi < 4; ++mi)
#pragma unroll
        for (int ni = 0; ni < 4; ++ni)
#pragma unroll
            for (int rr = 0; rr < 4; ++rr) {
                int mg = rowBase + wm * 64 + mi * 16 + (lane >> 4) * 4 + rr;
                int ng = colBase + wn * 64 + ni * 16 + (lane & 15);
                Y0p[(size_t)mg * 1024 + ng] = acc[mi][ni][rr] + bias[ng];
            }
}

// ---------------------------------------------------------------------------
// Pass 1: attended output + denominators (unchanged from r17).
// ---------------------------------------------------------------------------
__global__ __launch_bounds__(512, 4)
void attn_O(const u16* __restrict__ Qhi, const u16* __restrict__ Khi,
            const u16* __restrict__ VT, u16* __restrict__ Att,
            float* __restrict__ llog) {
    __shared__ char lds[49152];
    float* sOf = (float*)lds;
    float* sL2t = (float*)(lds + 35840);
    float* sL2f = (float*)(lds + 36864);

    const int t = threadIdx.x;
    const int w = t >> 6, lane = t & 63;
    const int g = lane >> 4, c16 = lane & 15;
    const int qt = blockIdx.x >> 6;
    const int g6 = blockIdx.x & 63;
    const int b = g6 >> 4, h = g6 & 15;
    const int qbase = qt * 128;
    const int wq = w >> 1, wk = w & 1;
    const int kswz = (g ^ (c16 & 7)) << 4;
    const int vsw0 = (((wk * 4 + 0 + (g >> 1)) ^ (c16 & 7)) << 4) | ((g & 1) << 3);
    const int vsw1 = (((wk * 4 + 2 + (g >> 1)) ^ (c16 & 7)) << 4) | ((g & 1) << 3);

    const char* Kh_g = (const char*)(Khi + (size_t)(b * 16 + h) * SKL * 64);
    const char* V_g  = (const char*)(VT + (size_t)(b * 16 + h) * 64 * SKL);

    s16x8 qh[2][2];
    const size_t qrowbase = (size_t)(b * 16 + h) * SQL + qbase;
#pragma unroll
    for (int qf = 0; qf < 2; ++qf) {
        size_t qo = (qrowbase + wq * 32 + qf * 16 + c16) * 64 + g * 8;
        qh[qf][0] = *(const s16x8*)&Qhi[qo];
        qh[qf][1] = *(const s16x8*)&Qhi[qo + 32];
    }

    stage8k(Kh_g, 128, lds, w, lane);
    stage8k(V_g, 4096, lds + 24576, w, lane);
    stage8k(Kh_g + 8192, 128, lds + 8192, w, lane);
    stage8k(V_g + 128, 4096, lds + 24576 + 8192, w, lane);

    const s16x4 onesf = {(short)0x3F80, (short)0x3F80, (short)0x3F80, (short)0x3F80};
    f32x4 oacc[2][4];
    f32x4 lacc[2];
    float lsum[2] = {0.f, 0.f};
#pragma unroll
    for (int qf = 0; qf < 2; ++qf) {
        lacc[qf] = (f32x4){0.f, 0.f, 0.f, 0.f};
#pragma unroll
        for (int i = 0; i < 4; ++i) oacc[qf][i] = (f32x4){0.f, 0.f, 0.f, 0.f};
    }

    int cur = 0;
    for (int c = 0; c < 32; ++c) {
        if (c < 31) { asm volatile("s_waitcnt vmcnt(2)" ::: "memory"); }
        else        { asm volatile("s_waitcnt vmcnt(0)" ::: "memory"); }
        SBAR();
        if (c + 2 < 32) {
            int nb = cur + 2; if (nb >= 3) nb -= 3;
            stage8k(Kh_g + (size_t)(c + 2) * 8192, 128, lds + nb * 8192, w, lane);
            stage8k(V_g + (size_t)(c + 2) * 128, 4096, lds + 24576 + nb * 8192, w, lane);
        }
        char* curK = lds + cur * 8192;
        char* curV = lds + 24576 + cur * 8192;
#pragma unroll
        for (int kf = 0; kf < 2; ++kf) {
            int kb = (wk * 32 + kf * 16 + c16) * 128 + kswz;
            s16x8 kh0 = *(const s16x8*)(curK + kb);
            s16x8 kh1 = *(const s16x8*)(curK + (kb ^ 64));
            s16x4 pb[2];
#pragma unroll
            for (int qf = 0; qf < 2; ++qf) {
                f32x4 s = {0.f, 0.f, 0.f, 0.f};
                s = mfma16(kh0, qh[qf][0], s);
                s = mfma16(kh1, qh[qf][1], s);
                float e0 = exp2f(s[0]);
                float e1 = exp2f(s[1]);
                float e2 = exp2f(s[2]);
                float e3 = exp2f(s[3]);
                lsum[qf] += (e0 + e1) + (e2 + e3);
                u32x2 pu = {permpack(e0, e1), permpack(e2, e3)};
                pb[qf] = __builtin_bit_cast(s16x4, pu);
                lacc[qf] = mfma16k16(onesf, pb[qf], lacc[qf]);
            }
            int vs = kf ? vsw1 : vsw0;
#pragma unroll
            for (int df = 0; df < 4; ++df) {
                s16x4 vf = *(const s16x4*)(curV + (df * 16 + c16) * 128 + vs);
                oacc[0][df] = mfma16k16(vf, pb[0], oacc[0][df]);
                oacc[1][df] = mfma16k16(vf, pb[1], oacc[1][df]);
            }
        }
        ++cur; if (cur == 3) cur = 0;
    }

#pragma unroll
    for (int qf = 0; qf < 2; ++qf) {
        lsum[qf] += __shfl_xor(lsum[qf], 16, 64);
        lsum[qf] += __shfl_xor(lsum[qf], 32, 64);
    }
    __syncthreads();
#pragma unroll
    for (int qf = 0; qf < 2; ++qf)
        if (g == 0) {
            sL2t[wk * 128 + wq * 32 + qf * 16 + c16] = lacc[qf][0];
            sL2f[wk * 128 + wq * 32 + qf * 16 + c16] = lsum[qf];
        }

#pragma unroll
    for (int half = 0; half < 2; ++half) {
        if (half) __syncthreads();
        if ((wq >> 1) == half) {
            int qlocal = (wq & 1) * 32 + c16;
#pragma unroll
            for (int qf = 0; qf < 2; ++qf)
#pragma unroll
                for (int df = 0; df < 4; ++df)
#pragma unroll
                    for (int r = 0; r < 4; ++r)
                        sOf[wk * 4352 + (df * 16 + g * 4 + r) * 68 + qlocal + qf * 16] =
                            oacc[qf][df][r];
        }
        __syncthreads();
        {
            int q = t >> 3, dg = t & 7;
            float lt = sL2t[half * 64 + q] + sL2t[128 + half * 64 + q];
            float linv = 1.f / lt;
            u16x8 ov;
#pragma unroll
            for (int i = 0; i < 8; ++i) {
                int d = dg * 8 + i;
                ov[i] = f2bf((sOf[d * 68 + q] + sOf[4352 + d * 68 + q]) * linv);
            }
            *(u16x8*)&Att[(size_t)(b * SQL + qbase + half * 64 + q) * EMBED + h * 64 + dg * 8] = ov;
            if (dg == 0) {
                float lf = sL2f[half * 64 + q] + sL2f[128 + half * 64 + q];
                llog[(size_t)(b * 16 + h) * SQL + qbase + half * 64 + q] = log2f(lf);
            }
        }
    }
}

// ---------------------------------------------------------------------------
// Pass 2: mean_attn (unchanged from r17).
// ---------------------------------------------------------------------------
__global__ __launch_bounds__(512, 4)
void attn_mean(const u16* __restrict__ Qhi, const u16* __restrict__ Khi,
               const float* __restrict__ llog, float* __restrict__ meanOut) {
    __shared__ char lds[81920];   // Q dbuf 2x16K @0; K tbuf 3x16K @32768

    const int t = threadIdx.x;
    const int w = t >> 6, lane = t & 63;
    const int g = lane >> 4, c16 = lane & 15;
    const int qt = blockIdx.x >> 6;
    const int low = blockIdx.x & 63;
    const int b = low >> 4, ks = low & 15;
    const int qbase = qt * 128;
    const int kbase = ks * 128;
    const int wq = w >> 1, wk = w & 1;
    const int kswz = (g ^ (c16 & 7)) << 4;

    const size_t QH_STRIDE = (size_t)SQL * 128;
    const size_t KH_STRIDE = (size_t)SKL * 128;
    const char* Qh_b = (const char*)(Qhi + ((size_t)(b * 16) * SQL + qbase) * 64);
    const char* Kh_b = (const char*)(Khi + ((size_t)(b * 16) * SKL + kbase) * 64);
    const float* ll_b = llog + (size_t)(b * 16) * SQL + qbase;

    f32x4 ma[2][4];
#pragma unroll
    for (int qf = 0; qf < 2; ++qf)
#pragma unroll
        for (int i = 0; i < 4; ++i) ma[qf][i] = (f32x4){0.f, 0.f, 0.f, 0.f};

    stage8k(Qh_b, 128, lds, w, lane);
    stage8k(Qh_b + 8192, 128, lds + 8192, w, lane);
    float lbA0 = ll_b[wq * 32 + c16];
    float lbA1 = ll_b[wq * 32 + 16 + c16];
    stage8k(Kh_b, 128, lds + 32768, w, lane);
    stage8k(Kh_b + 8192, 128, lds + 32768 + 8192, w, lane);
    stage8k(Qh_b + QH_STRIDE, 128, lds + 16384, w, lane);
    stage8k(Qh_b + QH_STRIDE + 8192, 128, lds + 16384 + 8192, w, lane);
    float lbB0 = ll_b[SQL + wq * 32 + c16];
    float lbB1 = ll_b[SQL + wq * 32 + 16 + c16];
    stage8k(Kh_b + KH_STRIDE, 128, lds + 32768 + 16384, w, lane);
    stage8k(Kh_b + KH_STRIDE + 8192, 128, lds + 32768 + 16384 + 8192, w, lane);

    int curK = 0;
    for (int h = 0; h < 16; ++h) {
        if (h < 15) { asm volatile("s_waitcnt vmcnt(4)" ::: "memory"); }
        else        { asm volatile("s_waitcnt vmcnt(0)" ::: "memory"); }
        SBAR();

        const char* sQ = lds + (h & 1) * 16384;
        s16x8 qa0, qa1, qc0, qc1;
        {
            int qb0 = (wq * 32 + c16) * 128 + kswz;
            qa0 = *(const s16x8*)(sQ + qb0);
            qa1 = *(const s16x8*)(sQ + (qb0 ^ 64));
            int qb1 = (wq * 32 + 16 + c16) * 128 + kswz;
            qc0 = *(const s16x8*)(sQ + qb1);
            qc1 = *(const s16x8*)(sQ + (qb1 ^ 64));
        }
        asm volatile("s_waitcnt lgkmcnt(0)" ::: "memory");
        SBAR();

        float lb0 = lbA0, lb1 = lbA1;
        lbA0 = lbB0; lbA1 = lbB1;

        if (h + 2 < 16) {
            const char* Qg = Qh_b + (size_t)(h + 2) * QH_STRIDE;
            char* qdst = lds + (h & 1) * 16384;
            stage8k(Qg, 128, qdst, w, lane);
            stage8k(Qg + 8192, 128, qdst + 8192, w, lane);
            lbB0 = ll_b[(size_t)(h + 2) * SQL + wq * 32 + c16];
            lbB1 = ll_b[(size_t)(h + 2) * SQL + wq * 32 + 16 + c16];
            const char* Kg = Kh_b + (size_t)(h + 2) * KH_STRIDE;
            int nb = curK + 2; if (nb >= 3) nb -= 3;
            char* kdst = lds + 32768 + nb * 16384;
            stage8k(Kg, 128, kdst, w, lane);
            stage8k(Kg + 8192, 128, kdst + 8192, w, lane);
        }

        const char* sK = lds + 32768 + curK * 16384;
#pragma unroll
        for (int kf = 0; kf < 4; ++kf) {
            int kb = (kf * 32 + wk * 16 + c16) * 128 + kswz;
            s16x8 kh0 = *(const s16x8*)(sK + kb);
            s16x8 kh1 = *(const s16x8*)(sK + (kb ^ 64));
            {
                f32x4 s = {0.f, 0.f, 0.f, 0.f};
                s = mfma16(kh0, qa0, s);
                s = mfma16(kh1, qa1, s);
                ma[0][kf][0] += exp2f(s[0] - lb0);
                ma[0][kf][1] += exp2f(s[1] - lb0);
                ma[0][kf][2] += exp2f(s[2] - lb0);
                ma[0][kf][3] += exp2f(s[3] - lb0);
            }
            {
                f32x4 s = {0.f, 0.f, 0.f, 0.f};
                s = mfma16(kh0, qc0, s);
                s = mfma16(kh1, qc1, s);
                ma[1][kf][0] += exp2f(s[0] - lb1);
                ma[1][kf][1] += exp2f(s[1] - lb1);
                ma[1][kf][2] += exp2f(s[2] - lb1);
                ma[1][kf][3] += exp2f(s[3] - lb1);
            }
        }
        ++curK; if (curK == 3) curK = 0;
    }

    const float s16c = 1.f / 16.f;
#pragma unroll
    for (int qf = 0; qf < 2; ++qf)
#pragma unroll
        for (int kf = 0; kf < 4; ++kf) {
            f32x4 m = ma[qf][kf];
            m[0] *= s16c; m[1] *= s16c; m[2] *= s16c; m[3] *= s16c;
            *(f32x4*)&meanOut[(size_t)(b * SQL + qbase + wq * 32 + qf * 16 + c16) * SKL +
                              kbase + kf * 32 + wk * 16 + g * 4] = m;
        }
}

// ---------------------------------------------------------------------------
extern "C" void kernel_launch(void* const* d_in, const int* in_sizes, int n_in,
                              void* d_out, int out_size, void* d_ws, size_t ws_size,
                              hipStream_t stream) {
    const float* query = (const float*)d_in[0];
    const float* key   = (const float*)d_in[1];
    const float* value = (const float*)d_in[2];
    const float* Wq = (const float*)d_in[3];
    const float* bq = (const float*)d_in[4];
    const float* Wk = (const float*)d_in[5];
    const float* bk = (const float*)d_in[6];
    const float* Wv = (const float*)d_in[7];
    const float* bv = (const float*)d_in[8];
    const float* Wo = (const float*)d_in[9];
    const float* bo = (const float*)d_in[10];

    float* out = (float*)d_out;                         // [4,1024,1024] f32
    float* meanOut = out + (size_t)BATCH * SQL * EMBED; // [4,1024,2048] f32

    u16* Qhi = (u16*)d_ws;                              // head-major [b][h][q][64], pre-scaled by PSC
    u16* Khi = Qhi + (size_t)4096 * 1024;               // [b][h][k][64]
    u16* VTh = Khi + (size_t)8192 * 1024;               // [b][h][d][2048]
    u16* Att = VTh + (size_t)8192 * 1024;               // [4096][1024] bf16
    float* llog = (float*)(Att + (size_t)4096 * 1024);  // [b*16+h][q]
    u16* Wqh = (u16*)(llog + 64 * 1024);                // bf16 weight planes
    u16* Wkh = Wqh + (size_t)1024 * 1024;
    u16* Wvh = Wkh + (size_t)1024 * 1024;
    u16* Woh = Wvh + (size_t)1024 * 1024;

    cvt_w<<<dim3(2048), 256, 0, stream>>>(Wq, Wk, Wv, Wo, Wqh, Wkh, Wvh, Woh);

    gemm_qkv<<<dim3(1280), 256, 0, stream>>>(query, key, value, Wqh, Wkh, Wvh,
                                             bq, bk, bv, Qhi, Khi, VTh);

    attn_O<<<dim3(512), dim3(512), 0, stream>>>(Qhi, Khi, VTh, Att, llog);
    attn_mean<<<dim3(512), dim3(512), 0, stream>>>(Qhi, Khi, llog, meanOut);

    gemm_oproj<<<dim3(8, 32), 256, 0, stream>>>(Att, Woh, bo, out);
}

// Round 19
// 223.505 us; speedup vs baseline: 1.1627x; 1.1627x over previous
//
#include <hip/hip_runtime.h>
#include <hip/hip_bf16.h>
#include <math.h>

#define EMBED 1024
#define NHEADS 16
#define HDIM 64
#define BATCH 4
#define SQL 1024
#define SKL 2048
#define PSC 0.18033688f   // 0.125 * log2(e)  (folded into Q projection)

typedef unsigned short u16;
typedef __attribute__((ext_vector_type(4))) float f32x4;
typedef __attribute__((ext_vector_type(8))) __bf16 bf16x8;
typedef __attribute__((ext_vector_type(8))) short s16x8;
typedef __attribute__((ext_vector_type(4))) short s16x4;
typedef __attribute__((ext_vector_type(8))) u16 u16x8;
typedef __attribute__((ext_vector_type(2))) unsigned u32x2;

__device__ __forceinline__ u16 f2bf(float x) {
    __hip_bfloat16 h = __float2bfloat16(x);
    return *reinterpret_cast<u16*>(&h);
}
__device__ __forceinline__ float bf2f(u16 u) {
    __hip_bfloat16 h;
    *reinterpret_cast<u16*>(&h) = u;
    return __bfloat162float(h);
}
// Truncation-pack: {bf16_trunc(e1), bf16_trunc(e0)} in one v_perm_b32.
__device__ __forceinline__ unsigned permpack(float e0, float e1) {
    return __builtin_amdgcn_perm(__builtin_bit_cast(unsigned, e1),
                                 __builtin_bit_cast(unsigned, e0), 0x07060302u);
}
__device__ __forceinline__ f32x4 mfma16(s16x8 a, s16x8 b, f32x4 c) {
    return __builtin_amdgcn_mfma_f32_16x16x32_bf16(
        __builtin_bit_cast(bf16x8, a), __builtin_bit_cast(bf16x8, b), c, 0, 0, 0);
}
__device__ __forceinline__ f32x4 mfma16k16(s16x4 a, s16x4 b, f32x4 c) {
    return __builtin_amdgcn_mfma_f32_16x16x16bf16_1k(a, b, c, 0, 0, 0);
}
__device__ __forceinline__ void gload16(const void* g, void* l) {
    __builtin_amdgcn_global_load_lds(
        (const __attribute__((address_space(1))) void*)g,
        (__attribute__((address_space(3))) void*)l, 16, 0, 0);
}
// Stage one 8KB plane (64 rows x 128B) with XOR-preswizzled source.
__device__ __forceinline__ void stage8k(const char* g, size_t rstrideB,
                                        char* ldsPlane, int w, int lane) {
    int r = w * 8 + (lane >> 3);
    int cs = (lane & 7) ^ (r & 7);
    gload16(g + (size_t)r * rstrideB + cs * 16, ldsPlane + (size_t)w * 1024);
}
#define SBAR() { __builtin_amdgcn_sched_barrier(0); \
    __builtin_amdgcn_s_barrier(); __builtin_amdgcn_sched_barrier(0); }

// ---------------------------------------------------------------------------
// cvt_w: all four weight matrices f32 -> bf16 (hi only, RNE).
// ---------------------------------------------------------------------------
__global__ __launch_bounds__(256)
void cvt_w(const float* __restrict__ Wq, const float* __restrict__ Wk,
           const float* __restrict__ Wv, const float* __restrict__ Wo,
           u16* __restrict__ Wqh, u16* __restrict__ Wkh,
           u16* __restrict__ Wvh, u16* __restrict__ Woh) {
    int bid = blockIdx.x;
    const float* src; u16* dh;
    if (bid < 512)       { src = Wq; dh = Wqh; }
    else if (bid < 1024) { bid -= 512;  src = Wk; dh = Wkh; }
    else if (bid < 1536) { bid -= 1024; src = Wv; dh = Wvh; }
    else                 { bid -= 1536; src = Wo; dh = Woh; }
    size_t i = ((size_t)bid * 256 + threadIdx.x) * 8;
    float4 a = *(const float4*)&src[i];
    float4 b = *(const float4*)&src[i + 4];
    float v[8] = {a.x, a.y, a.z, a.w, b.x, b.y, b.z, b.w};
    u16x8 hi;
#pragma unroll
    for (int j = 0; j < 8; ++j) hi[j] = f2bf(v[j]);
    *(u16x8*)&dh[i] = hi;
}

// ---------------------------------------------------------------------------
// Fused Q+K projection: ONE code path (A f32 + cvt, W bf16 direct, bf16
// head-major out). Role selects only uniform pointers/scalars.
//   blocks [0,256):   Q (scale=PSC, bshift=10)
//   blocks [256,768): K (scale=1.0, bshift=11)
// 768 blocks = 3 blocks/CU. 128x128 tile, BK=32, 2-deep register prefetch.
// ---------------------------------------------------------------------------
#define QK_LOAD(S, kk) { \
    _Pragma("unroll") for (int j = 0; j < 4; ++j) \
        *(float4*)&ax##S[j * 4] = *(const float4*)&Af[(size_t)(rowBase + srow) * 1024 + (kk) + sc + j * 4]; \
    wh##S##0 = *(const u16x8*)&Wu[(size_t)(colBase + srow) * 1024 + (kk) + sc]; \
    wh##S##1 = *(const u16x8*)&Wu[(size_t)(colBase + srow) * 1024 + (kk) + sc + 8]; }

#define QK_WRITE(S) { \
    u16x8 h0, h1; \
    _Pragma("unroll") for (int j = 0; j < 8; ++j) { \
        h0[j] = f2bf(ax##S[j]); h1[j] = f2bf(ax##S[j + 8]); } \
    *(u16x8*)&sA[srow * 40 + sc] = h0; \
    *(u16x8*)&sA[srow * 40 + sc + 8] = h1; \
    *(u16x8*)&sB[srow * 40 + sc] = wh##S##0; \
    *(u16x8*)&sB[srow * 40 + sc + 8] = wh##S##1; }

#define GEMM_COMPUTE() { \
    s16x8 afh[4], bfh[4]; \
    _Pragma("unroll") for (int mi = 0; mi < 4; ++mi) { \
        int ai = (wm * 64 + mi * 16 + (lane & 15)) * 40 + (lane >> 4) * 8; \
        afh[mi] = *(const s16x8*)&sA[ai]; \
    } \
    _Pragma("unroll") for (int ni = 0; ni < 4; ++ni) { \
        int bi = (wn * 64 + ni * 16 + (lane & 15)) * 40 + (lane >> 4) * 8; \
        bfh[ni] = *(const s16x8*)&sB[bi]; \
    } \
    _Pragma("unroll") for (int mi = 0; mi < 4; ++mi) \
        _Pragma("unroll") for (int ni = 0; ni < 4; ++ni) \
            acc[mi][ni] = mfma16(afh[mi], bfh[ni], acc[mi][ni]); }

__global__ __launch_bounds__(256)
void gemm_qk(const float* __restrict__ query, const float* __restrict__ key,
             const u16* __restrict__ Wqh, const u16* __restrict__ Wkh,
             const float* __restrict__ bq, const float* __restrict__ bk,
             u16* __restrict__ Qhi, u16* __restrict__ Khi) {
    __shared__ u16 sA[128 * 40];
    __shared__ u16 sB[128 * 40];

    const int t = threadIdx.x;
    const int lane = t & 63;
    const int w = t >> 6;
    const int wm = w >> 1, wn = w & 1;
    const int srow = t >> 1;
    const int sc = (t & 1) * 16;

    const int bid = blockIdx.x;
    const int isK = bid >= 256;
    const int r = isK ? bid - 256 : bid;
    const int rowBase = (r >> 3) * 128;
    const int colBase = (r & 7) * 128;
    const float* Af = isK ? key : query;
    const u16* Wu = isK ? Wkh : Wqh;
    const float* bias = isK ? bk : bq;
    const float scale = isK ? 1.0f : PSC;
    const int bshift = isK ? 11 : 10;
    u16* Yout = isK ? Khi : Qhi;

    f32x4 acc[4][4];
#pragma unroll
    for (int i = 0; i < 4; ++i)
#pragma unroll
        for (int j = 0; j < 4; ++j) acc[i][j] = (f32x4){0.f, 0.f, 0.f, 0.f};

    float ax0[16], ax1[16];
    u16x8 wh00, wh01, wh10, wh11;

    QK_LOAD(0, 0)
    QK_LOAD(1, 32)

    for (int k0 = 0; k0 < 1024; k0 += 64) {
        __syncthreads();
        QK_WRITE(0)
        __syncthreads();
        if (k0 + 64 < 1024) QK_LOAD(0, k0 + 64)
        GEMM_COMPUTE()
        __syncthreads();
        QK_WRITE(1)
        __syncthreads();
        if (k0 + 96 < 1024) QK_LOAD(1, k0 + 96)
        GEMM_COMPUTE()
    }

#pragma unroll
    for (int mi = 0; mi < 4; ++mi)
#pragma unroll
        for (int ni = 0; ni < 4; ++ni)
#pragma unroll
            for (int rr = 0; rr < 4; ++rr) {
                int mg = rowBase + wm * 64 + mi * 16 + (lane >> 4) * 4 + rr;
                int ng = colBase + wn * 64 + ni * 16 + (lane & 15);
                float y = (acc[mi][ni][rr] + bias[ng]) * scale;
                int bb = mg >> bshift, s = mg & ((1 << bshift) - 1);
                size_t idx = ((((size_t)(bb * 16 + (ng >> 6))) << bshift) + s) * 64 + (ng & 63);
                Yout[idx] = f2bf(y);
            }
}

// ---------------------------------------------------------------------------
// V-projection: VTh = Wvh @ value^T + bv[row], V^T head-major out.
// (A = Wvh bf16 direct, W = value f32 + cvt.)  r17 template, fixed modes.
// ---------------------------------------------------------------------------
__global__ __launch_bounds__(256)
void gemm_vproj(const u16* __restrict__ Au, const float* __restrict__ Wf,
                const float* __restrict__ bias, u16* __restrict__ VTh) {
    __shared__ u16 sA[128 * 40];
    __shared__ u16 sB[128 * 40];

    const int t = threadIdx.x;
    const int lane = t & 63;
    const int w = t >> 6;
    const int wm = w >> 1, wn = w & 1;
    const int rowBase = blockIdx.y * 128;
    const int colBase = blockIdx.x * 128;
    const int srow = t >> 1;
    const int sc = (t & 1) * 16;

    f32x4 acc[4][4];
#pragma unroll
    for (int i = 0; i < 4; ++i)
#pragma unroll
        for (int j = 0; j < 4; ++j) acc[i][j] = (f32x4){0.f, 0.f, 0.f, 0.f};

    u16x8 au00, au01, au10, au11;
    float bx0[16], bx1[16];

#define VP_LOAD(S, kk) { \
    au##S##0 = *(const u16x8*)&Au[(size_t)(rowBase + srow) * 1024 + (kk) + sc]; \
    au##S##1 = *(const u16x8*)&Au[(size_t)(rowBase + srow) * 1024 + (kk) + sc + 8]; \
    _Pragma("unroll") for (int j = 0; j < 4; ++j) \
        *(float4*)&bx##S[j * 4] = *(const float4*)&Wf[(size_t)(colBase + srow) * 1024 + (kk) + sc + j * 4]; }
#define VP_WRITE(S) { \
    *(u16x8*)&sA[srow * 40 + sc] = au##S##0; \
    *(u16x8*)&sA[srow * 40 + sc + 8] = au##S##1; \
    u16x8 b0, b1; \
    _Pragma("unroll") for (int j = 0; j < 8; ++j) { \
        b0[j] = f2bf(bx##S[j]); b1[j] = f2bf(bx##S[j + 8]); } \
    *(u16x8*)&sB[srow * 40 + sc] = b0; \
    *(u16x8*)&sB[srow * 40 + sc + 8] = b1; }

    VP_LOAD(0, 0)
    VP_LOAD(1, 32)

    for (int k0 = 0; k0 < 1024; k0 += 64) {
        __syncthreads();
        VP_WRITE(0)
        __syncthreads();
        if (k0 + 64 < 1024) VP_LOAD(0, k0 + 64)
        GEMM_COMPUTE()
        __syncthreads();
        VP_WRITE(1)
        __syncthreads();
        if (k0 + 96 < 1024) VP_LOAD(1, k0 + 96)
        GEMM_COMPUTE()
    }

#pragma unroll
    for (int mi = 0; mi < 4; ++mi)
#pragma unroll
        for (int ni = 0; ni < 4; ++ni)
#pragma unroll
            for (int rr = 0; rr < 4; ++rr) {
                int mg = rowBase + wm * 64 + mi * 16 + (lane >> 4) * 4 + rr;
                int ng = colBase + wn * 64 + ni * 16 + (lane & 15);
                float y = acc[mi][ni][rr] + bias[mg];
                size_t idx = ((size_t)((ng >> 11) * 16 + (mg >> 6)) * 64 + (mg & 63)) * 2048 + (ng & 2047);
                VTh[idx] = f2bf(y);
            }
}

// ---------------------------------------------------------------------------
// O-projection GEMM: out = Att @ Woh^T + bo, f32 output. (r17 unchanged.)
// ---------------------------------------------------------------------------
__global__ __launch_bounds__(256)
void gemm_oproj(const u16* __restrict__ Au, const u16* __restrict__ Wu,
                const float* __restrict__ bias, float* __restrict__ Y0p) {
    __shared__ u16 sA[128 * 40];
    __shared__ u16 sB[128 * 40];

    const int t = threadIdx.x;
    const int lane = t & 63;
    const int w = t >> 6;
    const int wm = w >> 1, wn = w & 1;
    const int rowBase = blockIdx.y * 128;
    const int colBase = blockIdx.x * 128;
    const int srow = t >> 1;
    const int sc = (t & 1) * 16;

    f32x4 acc[4][4];
#pragma unroll
    for (int i = 0; i < 4; ++i)
#pragma unroll
        for (int j = 0; j < 4; ++j) acc[i][j] = (f32x4){0.f, 0.f, 0.f, 0.f};

    u16x8 au00, au01, au10, au11;
    u16x8 wh00, wh01, wh10, wh11;

#define OP_LOAD(S, kk) { \
    au##S##0 = *(const u16x8*)&Au[(size_t)(rowBase + srow) * 1024 + (kk) + sc]; \
    au##S##1 = *(const u16x8*)&Au[(size_t)(rowBase + srow) * 1024 + (kk) + sc + 8]; \
    wh##S##0 = *(const u16x8*)&Wu[(size_t)(colBase + srow) * 1024 + (kk) + sc]; \
    wh##S##1 = *(const u16x8*)&Wu[(size_t)(colBase + srow) * 1024 + (kk) + sc + 8]; }
#define OP_WRITE(S) { \
    *(u16x8*)&sA[srow * 40 + sc] = au##S##0; \
    *(u16x8*)&sA[srow * 40 + sc + 8] = au##S##1; \
    *(u16x8*)&sB[srow * 40 + sc] = wh##S##0; \
    *(u16x8*)&sB[srow * 40 + sc + 8] = wh##S##1; }

    OP_LOAD(0, 0)
    OP_LOAD(1, 32)

    for (int k0 = 0; k0 < 1024; k0 += 64) {
        __syncthreads();
        OP_WRITE(0)
        __syncthreads();
        if (k0 + 64 < 1024) OP_LOAD(0, k0 + 64)
        GEMM_COMPUTE()
        __syncthreads();
        OP_WRITE(1)
        __syncthreads();
        if (k0 + 96 < 1024) OP_LOAD(1, k0 + 96)
        GEMM_COMPUTE()
    }

#pragma unroll
    for (int mi = 0; mi < 4; ++mi)
#pragma unroll
        for (int ni = 0; ni < 4; ++ni)
#pragma unroll
            for (int rr = 0; rr < 4; ++rr) {
                int mg = rowBase + wm * 64 + mi * 16 + (lane >> 4) * 4 + rr;
                int ng = colBase + wn * 64 + ni * 16 + (lane & 15);
                Y0p[(size_t)mg * 1024 + ng] = acc[mi][ni][rr] + bias[ng];
            }
}

// ---------------------------------------------------------------------------
// Pass 1: attended output + denominators (unchanged from r17).
// ---------------------------------------------------------------------------
__global__ __launch_bounds__(512, 4)
void attn_O(const u16* __restrict__ Qhi, const u16* __restrict__ Khi,
            const u16* __restrict__ VT, u16* __restrict__ Att,
            float* __restrict__ llog) {
    __shared__ char lds[49152];
    float* sOf = (float*)lds;
    float* sL2t = (float*)(lds + 35840);
    float* sL2f = (float*)(lds + 36864);

    const int t = threadIdx.x;
    const int w = t >> 6, lane = t & 63;
    const int g = lane >> 4, c16 = lane & 15;
    const int qt = blockIdx.x >> 6;
    const int g6 = blockIdx.x & 63;
    const int b = g6 >> 4, h = g6 & 15;
    const int qbase = qt * 128;
    const int wq = w >> 1, wk = w & 1;
    const int kswz = (g ^ (c16 & 7)) << 4;
    const int vsw0 = (((wk * 4 + 0 + (g >> 1)) ^ (c16 & 7)) << 4) | ((g & 1) << 3);
    const int vsw1 = (((wk * 4 + 2 + (g >> 1)) ^ (c16 & 7)) << 4) | ((g & 1) << 3);

    const char* Kh_g = (const char*)(Khi + (size_t)(b * 16 + h) * SKL * 64);
    const char* V_g  = (const char*)(VT + (size_t)(b * 16 + h) * 64 * SKL);

    s16x8 qh[2][2];
    const size_t qrowbase = (size_t)(b * 16 + h) * SQL + qbase;
#pragma unroll
    for (int qf = 0; qf < 2; ++qf) {
        size_t qo = (qrowbase + wq * 32 + qf * 16 + c16) * 64 + g * 8;
        qh[qf][0] = *(const s16x8*)&Qhi[qo];
        qh[qf][1] = *(const s16x8*)&Qhi[qo + 32];
    }

    stage8k(Kh_g, 128, lds, w, lane);
    stage8k(V_g, 4096, lds + 24576, w, lane);
    stage8k(Kh_g + 8192, 128, lds + 8192, w, lane);
    stage8k(V_g + 128, 4096, lds + 24576 + 8192, w, lane);

    const s16x4 onesf = {(short)0x3F80, (short)0x3F80, (short)0x3F80, (short)0x3F80};
    f32x4 oacc[2][4];
    f32x4 lacc[2];
    float lsum[2] = {0.f, 0.f};
#pragma unroll
    for (int qf = 0; qf < 2; ++qf) {
        lacc[qf] = (f32x4){0.f, 0.f, 0.f, 0.f};
#pragma unroll
        for (int i = 0; i < 4; ++i) oacc[qf][i] = (f32x4){0.f, 0.f, 0.f, 0.f};
    }

    int cur = 0;
    for (int c = 0; c < 32; ++c) {
        if (c < 31) { asm volatile("s_waitcnt vmcnt(2)" ::: "memory"); }
        else        { asm volatile("s_waitcnt vmcnt(0)" ::: "memory"); }
        SBAR();
        if (c + 2 < 32) {
            int nb = cur + 2; if (nb >= 3) nb -= 3;
            stage8k(Kh_g + (size_t)(c + 2) * 8192, 128, lds + nb * 8192, w, lane);
            stage8k(V_g + (size_t)(c + 2) * 128, 4096, lds + 24576 + nb * 8192, w, lane);
        }
        char* curK = lds + cur * 8192;
        char* curV = lds + 24576 + cur * 8192;
#pragma unroll
        for (int kf = 0; kf < 2; ++kf) {
            int kb = (wk * 32 + kf * 16 + c16) * 128 + kswz;
            s16x8 kh0 = *(const s16x8*)(curK + kb);
            s16x8 kh1 = *(const s16x8*)(curK + (kb ^ 64));
            s16x4 pb[2];
#pragma unroll
            for (int qf = 0; qf < 2; ++qf) {
                f32x4 s = {0.f, 0.f, 0.f, 0.f};
                s = mfma16(kh0, qh[qf][0], s);
                s = mfma16(kh1, qh[qf][1], s);
                float e0 = exp2f(s[0]);
                float e1 = exp2f(s[1]);
                float e2 = exp2f(s[2]);
                float e3 = exp2f(s[3]);
                lsum[qf] += (e0 + e1) + (e2 + e3);
                u32x2 pu = {permpack(e0, e1), permpack(e2, e3)};
                pb[qf] = __builtin_bit_cast(s16x4, pu);
                lacc[qf] = mfma16k16(onesf, pb[qf], lacc[qf]);
            }
            int vs = kf ? vsw1 : vsw0;
#pragma unroll
            for (int df = 0; df < 4; ++df) {
                s16x4 vf = *(const s16x4*)(curV + (df * 16 + c16) * 128 + vs);
                oacc[0][df] = mfma16k16(vf, pb[0], oacc[0][df]);
                oacc[1][df] = mfma16k16(vf, pb[1], oacc[1][df]);
            }
        }
        ++cur; if (cur == 3) cur = 0;
    }

#pragma unroll
    for (int qf = 0; qf < 2; ++qf) {
        lsum[qf] += __shfl_xor(lsum[qf], 16, 64);
        lsum[qf] += __shfl_xor(lsum[qf], 32, 64);
    }
    __syncthreads();
#pragma unroll
    for (int qf = 0; qf < 2; ++qf)
        if (g == 0) {
            sL2t[wk * 128 + wq * 32 + qf * 16 + c16] = lacc[qf][0];
            sL2f[wk * 128 + wq * 32 + qf * 16 + c16] = lsum[qf];
        }

#pragma unroll
    for (int half = 0; half < 2; ++half) {
        if (half) __syncthreads();
        if ((wq >> 1) == half) {
            int qlocal = (wq & 1) * 32 + c16;
#pragma unroll
            for (int qf = 0; qf < 2; ++qf)
#pragma unroll
                for (int df = 0; df < 4; ++df)
#pragma unroll
                    for (int r = 0; r < 4; ++r)
                        sOf[wk * 4352 + (df * 16 + g * 4 + r) * 68 + qlocal + qf * 16] =
                            oacc[qf][df][r];
        }
        __syncthreads();
        {
            int q = t >> 3, dg = t & 7;
            float lt = sL2t[half * 64 + q] + sL2t[128 + half * 64 + q];
            float linv = 1.f / lt;
            u16x8 ov;
#pragma unroll
            for (int i = 0; i < 8; ++i) {
                int d = dg * 8 + i;
                ov[i] = f2bf((sOf[d * 68 + q] + sOf[4352 + d * 68 + q]) * linv);
            }
            *(u16x8*)&Att[(size_t)(b * SQL + qbase + half * 64 + q) * EMBED + h * 64 + dg * 8] = ov;
            if (dg == 0) {
                float lf = sL2f[half * 64 + q] + sL2f[128 + half * 64 + q];
                llog[(size_t)(b * 16 + h) * SQL + qbase + half * 64 + q] = log2f(lf);
            }
        }
    }
}

// ---------------------------------------------------------------------------
// Pass 2: mean_attn (unchanged from r17).
// ---------------------------------------------------------------------------
__global__ __launch_bounds__(512, 4)
void attn_mean(const u16* __restrict__ Qhi, const u16* __restrict__ Khi,
               const float* __restrict__ llog, float* __restrict__ meanOut) {
    __shared__ char lds[81920];   // Q dbuf 2x16K @0; K tbuf 3x16K @32768

    const int t = threadIdx.x;
    const int w = t >> 6, lane = t & 63;
    const int g = lane >> 4, c16 = lane & 15;
    const int qt = blockIdx.x >> 6;
    const int low = blockIdx.x & 63;
    const int b = low >> 4, ks = low & 15;
    const int qbase = qt * 128;
    const int kbase = ks * 128;
    const int wq = w >> 1, wk = w & 1;
    const int kswz = (g ^ (c16 & 7)) << 4;

    const size_t QH_STRIDE = (size_t)SQL * 128;
    const size_t KH_STRIDE = (size_t)SKL * 128;
    const char* Qh_b = (const char*)(Qhi + ((size_t)(b * 16) * SQL + qbase) * 64);
    const char* Kh_b = (const char*)(Khi + ((size_t)(b * 16) * SKL + kbase) * 64);
    const float* ll_b = llog + (size_t)(b * 16) * SQL + qbase;

    f32x4 ma[2][4];
#pragma unroll
    for (int qf = 0; qf < 2; ++qf)
#pragma unroll
        for (int i = 0; i < 4; ++i) ma[qf][i] = (f32x4){0.f, 0.f, 0.f, 0.f};

    stage8k(Qh_b, 128, lds, w, lane);
    stage8k(Qh_b + 8192, 128, lds + 8192, w, lane);
    float lbA0 = ll_b[wq * 32 + c16];
    float lbA1 = ll_b[wq * 32 + 16 + c16];
    stage8k(Kh_b, 128, lds + 32768, w, lane);
    stage8k(Kh_b + 8192, 128, lds + 32768 + 8192, w, lane);
    stage8k(Qh_b + QH_STRIDE, 128, lds + 16384, w, lane);
    stage8k(Qh_b + QH_STRIDE + 8192, 128, lds + 16384 + 8192, w, lane);
    float lbB0 = ll_b[SQL + wq * 32 + c16];
    float lbB1 = ll_b[SQL + wq * 32 + 16 + c16];
    stage8k(Kh_b + KH_STRIDE, 128, lds + 32768 + 16384, w, lane);
    stage8k(Kh_b + KH_STRIDE + 8192, 128, lds + 32768 + 16384 + 8192, w, lane);

    int curK = 0;
    for (int h = 0; h < 16; ++h) {
        if (h < 15) { asm volatile("s_waitcnt vmcnt(4)" ::: "memory"); }
        else        { asm volatile("s_waitcnt vmcnt(0)" ::: "memory"); }
        SBAR();

        const char* sQ = lds + (h & 1) * 16384;
        s16x8 qa0, qa1, qc0, qc1;
        {
            int qb0 = (wq * 32 + c16) * 128 + kswz;
            qa0 = *(const s16x8*)(sQ + qb0);
            qa1 = *(const s16x8*)(sQ + (qb0 ^ 64));
            int qb1 = (wq * 32 + 16 + c16) * 128 + kswz;
            qc0 = *(const s16x8*)(sQ + qb1);
            qc1 = *(const s16x8*)(sQ + (qb1 ^ 64));
        }
        asm volatile("s_waitcnt lgkmcnt(0)" ::: "memory");
        SBAR();

        float lb0 = lbA0, lb1 = lbA1;
        lbA0 = lbB0; lbA1 = lbB1;

        if (h + 2 < 16) {
            const char* Qg = Qh_b + (size_t)(h + 2) * QH_STRIDE;
            char* qdst = lds + (h & 1) * 16384;
            stage8k(Qg, 128, qdst, w, lane);
            stage8k(Qg + 8192, 128, qdst + 8192, w, lane);
            lbB0 = ll_b[(size_t)(h + 2) * SQL + wq * 32 + c16];
            lbB1 = ll_b[(size_t)(h + 2) * SQL + wq * 32 + 16 + c16];
            const char* Kg = Kh_b + (size_t)(h + 2) * KH_STRIDE;
            int nb = curK + 2; if (nb >= 3) nb -= 3;
            char* kdst = lds + 32768 + nb * 16384;
            stage8k(Kg, 128, kdst, w, lane);
            stage8k(Kg + 8192, 128, kdst + 8192, w, lane);
        }

        const char* sK = lds + 32768 + curK * 16384;
#pragma unroll
        for (int kf = 0; kf < 4; ++kf) {
            int kb = (kf * 32 + wk * 16 + c16) * 128 + kswz;
            s16x8 kh0 = *(const s16x8*)(sK + kb);
            s16x8 kh1 = *(const s16x8*)(sK + (kb ^ 64));
            {
                f32x4 s = {0.f, 0.f, 0.f, 0.f};
                s = mfma16(kh0, qa0, s);
                s = mfma16(kh1, qa1, s);
                ma[0][kf][0] += exp2f(s[0] - lb0);
                ma[0][kf][1] += exp2f(s[1] - lb0);
                ma[0][kf][2] += exp2f(s[2] - lb0);
                ma[0][kf][3] += exp2f(s[3] - lb0);
            }
            {
                f32x4 s = {0.f, 0.f, 0.f, 0.f};
                s = mfma16(kh0, qc0, s);
                s = mfma16(kh1, qc1, s);
                ma[1][kf][0] += exp2f(s[0] - lb1);
                ma[1][kf][1] += exp2f(s[1] - lb1);
                ma[1][kf][2] += exp2f(s[2] - lb1);
                ma[1][kf][3] += exp2f(s[3] - lb1);
            }
        }
        ++curK; if (curK == 3) curK = 0;
    }

    const float s16c = 1.f / 16.f;
#pragma unroll
    for (int qf = 0; qf < 2; ++qf)
#pragma unroll
        for (int kf = 0; kf < 4; ++kf) {
            f32x4 m = ma[qf][kf];
            m[0] *= s16c; m[1] *= s16c; m[2] *= s16c; m[3] *= s16c;
            *(f32x4*)&meanOut[(size_t)(b * SQL + qbase + wq * 32 + qf * 16 + c16) * SKL +
                              kbase + kf * 32 + wk * 16 + g * 4] = m;
        }
}

// ---------------------------------------------------------------------------
extern "C" void kernel_launch(void* const* d_in, const int* in_sizes, int n_in,
                              void* d_out, int out_size, void* d_ws, size_t ws_size,
                              hipStream_t stream) {
    const float* query = (const float*)d_in[0];
    const float* key   = (const float*)d_in[1];
    const float* value = (const float*)d_in[2];
    const float* Wq = (const float*)d_in[3];
    const float* bq = (const float*)d_in[4];
    const float* Wk = (const float*)d_in[5];
    const float* bk = (const float*)d_in[6];
    const float* Wv = (const float*)d_in[7];
    const float* bv = (const float*)d_in[8];
    const float* Wo = (const float*)d_in[9];
    const float* bo = (const float*)d_in[10];

    float* out = (float*)d_out;                         // [4,1024,1024] f32
    float* meanOut = out + (size_t)BATCH * SQL * EMBED; // [4,1024,2048] f32

    u16* Qhi = (u16*)d_ws;                              // head-major [b][h][q][64], pre-scaled by PSC
    u16* Khi = Qhi + (size_t)4096 * 1024;               // [b][h][k][64]
    u16* VTh = Khi + (size_t)8192 * 1024;               // [b][h][d][2048]
    u16* Att = VTh + (size_t)8192 * 1024;               // [4096][1024] bf16
    float* llog = (float*)(Att + (size_t)4096 * 1024);  // [b*16+h][q]
    u16* Wqh = (u16*)(llog + 64 * 1024);                // bf16 weight planes
    u16* Wkh = Wqh + (size_t)1024 * 1024;
    u16* Wvh = Wkh + (size_t)1024 * 1024;
    u16* Woh = Wvh + (size_t)1024 * 1024;

    cvt_w<<<dim3(2048), 256, 0, stream>>>(Wq, Wk, Wv, Wo, Wqh, Wkh, Wvh, Woh);

    gemm_qk<<<dim3(768), 256, 0, stream>>>(query, key, Wqh, Wkh, bq, bk, Qhi, Khi);
    gemm_vproj<<<dim3(64, 8), 256, 0, stream>>>(Wvh, value, bv, VTh);

    attn_O<<<dim3(512), dim3(512), 0, stream>>>(Qhi, Khi, VTh, Att, llog);
    attn_mean<<<dim3(512), dim3(512), 0, stream>>>(Qhi, Khi, llog, meanOut);

    gemm_oproj<<<dim3(8, 32), 256, 0, stream>>>(Att, Woh, bo, out);
}

// Round 20
// 208.684 us; speedup vs baseline: 1.2452x; 1.0710x over previous
//
#include <hip/hip_runtime.h>
#include <hip/hip_bf16.h>
#include <math.h>

#define EMBED 1024
#define NHEADS 16
#define HDIM 64
#define BATCH 4
#define SQL 1024
#define SKL 2048
#define PSC 0.18033688f   // 0.125 * log2(e)  (folded into Q projection)

typedef unsigned short u16;
typedef __attribute__((ext_vector_type(4))) float f32x4;
typedef __attribute__((ext_vector_type(8))) __bf16 bf16x8;
typedef __attribute__((ext_vector_type(8))) short s16x8;
typedef __attribute__((ext_vector_type(4))) short s16x4;
typedef __attribute__((ext_vector_type(8))) u16 u16x8;
typedef __attribute__((ext_vector_type(2))) unsigned u32x2;

__device__ __forceinline__ u16 f2bf(float x) {
    __hip_bfloat16 h = __float2bfloat16(x);
    return *reinterpret_cast<u16*>(&h);
}
__device__ __forceinline__ float bf2f(u16 u) {
    __hip_bfloat16 h;
    *reinterpret_cast<u16*>(&h) = u;
    return __bfloat162float(h);
}
// Truncation-pack: {bf16_trunc(e1), bf16_trunc(e0)} in one v_perm_b32.
__device__ __forceinline__ unsigned permpack(float e0, float e1) {
    return __builtin_amdgcn_perm(__builtin_bit_cast(unsigned, e1),
                                 __builtin_bit_cast(unsigned, e0), 0x07060302u);
}
__device__ __forceinline__ f32x4 mfma16(s16x8 a, s16x8 b, f32x4 c) {
    return __builtin_amdgcn_mfma_f32_16x16x32_bf16(
        __builtin_bit_cast(bf16x8, a), __builtin_bit_cast(bf16x8, b), c, 0, 0, 0);
}
__device__ __forceinline__ f32x4 mfma16k16(s16x4 a, s16x4 b, f32x4 c) {
    return __builtin_amdgcn_mfma_f32_16x16x16bf16_1k(a, b, c, 0, 0, 0);
}
__device__ __forceinline__ void gload16(const void* g, void* l) {
    __builtin_amdgcn_global_load_lds(
        (const __attribute__((address_space(1))) void*)g,
        (__attribute__((address_space(3))) void*)l, 16, 0, 0);
}
// Stage one 8KB plane (64 rows x 128B) with XOR-preswizzled source.
__device__ __forceinline__ void stage8k(const char* g, size_t rstrideB,
                                        char* ldsPlane, int w, int lane) {
    int r = w * 8 + (lane >> 3);
    int cs = (lane & 7) ^ (r & 7);
    gload16(g + (size_t)r * rstrideB + cs * 16, ldsPlane + (size_t)w * 1024);
}
#define SBAR() { __builtin_amdgcn_sched_barrier(0); \
    __builtin_amdgcn_s_barrier(); __builtin_amdgcn_sched_barrier(0); }

// ---------------------------------------------------------------------------
// cvt_w: all four weight matrices f32 -> bf16 (hi only, RNE).
// ---------------------------------------------------------------------------
__global__ __launch_bounds__(256)
void cvt_w(const float* __restrict__ Wq, const float* __restrict__ Wk,
           const float* __restrict__ Wv, const float* __restrict__ Wo,
           u16* __restrict__ Wqh, u16* __restrict__ Wkh,
           u16* __restrict__ Wvh, u16* __restrict__ Woh) {
    int bid = blockIdx.x;
    const float* src; u16* dh;
    if (bid < 512)       { src = Wq; dh = Wqh; }
    else if (bid < 1024) { bid -= 512;  src = Wk; dh = Wkh; }
    else if (bid < 1536) { bid -= 1024; src = Wv; dh = Wvh; }
    else                 { bid -= 1536; src = Wo; dh = Woh; }
    size_t i = ((size_t)bid * 256 + threadIdx.x) * 8;
    float4 a = *(const float4*)&src[i];
    float4 b = *(const float4*)&src[i + 4];
    float v[8] = {a.x, a.y, a.z, a.w, b.x, b.y, b.z, b.w};
    u16x8 hi;
#pragma unroll
    for (int j = 0; j < 8; ++j) hi[j] = f2bf(v[j]);
    *(u16x8*)&dh[i] = hi;
}

// ---------------------------------------------------------------------------
// Fused Q+K projection with XCD-aware block remap: p = bid % 96 is the
// row-panel (96 % 8 == 0, so all 8 column-blocks of panel p have the same
// bid % 8 -> land on ONE XCD; its 512KB A-panel is fetched from HBM once
// and served 8x from that XCD's L2). col = bid / 96.
//   p in [0,32):  Q row-panel (scale=PSC, bshift=10)
//   p in [32,96): K row-panel (scale=1.0, bshift=11)
// ---------------------------------------------------------------------------
#define QK_LOAD(S, kk) { \
    _Pragma("unroll") for (int j = 0; j < 4; ++j) \
        *(float4*)&ax##S[j * 4] = *(const float4*)&Af[(size_t)(rowBase + srow) * 1024 + (kk) + sc + j * 4]; \
    wh##S##0 = *(const u16x8*)&Wu[(size_t)(colBase + srow) * 1024 + (kk) + sc]; \
    wh##S##1 = *(const u16x8*)&Wu[(size_t)(colBase + srow) * 1024 + (kk) + sc + 8]; }

#define QK_WRITE(S) { \
    u16x8 h0, h1; \
    _Pragma("unroll") for (int j = 0; j < 8; ++j) { \
        h0[j] = f2bf(ax##S[j]); h1[j] = f2bf(ax##S[j + 8]); } \
    *(u16x8*)&sA[srow * 40 + sc] = h0; \
    *(u16x8*)&sA[srow * 40 + sc + 8] = h1; \
    *(u16x8*)&sB[srow * 40 + sc] = wh##S##0; \
    *(u16x8*)&sB[srow * 40 + sc + 8] = wh##S##1; }

#define GEMM_COMPUTE() { \
    s16x8 afh[4], bfh[4]; \
    _Pragma("unroll") for (int mi = 0; mi < 4; ++mi) { \
        int ai = (wm * 64 + mi * 16 + (lane & 15)) * 40 + (lane >> 4) * 8; \
        afh[mi] = *(const s16x8*)&sA[ai]; \
    } \
    _Pragma("unroll") for (int ni = 0; ni < 4; ++ni) { \
        int bi = (wn * 64 + ni * 16 + (lane & 15)) * 40 + (lane >> 4) * 8; \
        bfh[ni] = *(const s16x8*)&sB[bi]; \
    } \
    _Pragma("unroll") for (int mi = 0; mi < 4; ++mi) \
        _Pragma("unroll") for (int ni = 0; ni < 4; ++ni) \
            acc[mi][ni] = mfma16(afh[mi], bfh[ni], acc[mi][ni]); }

__global__ __launch_bounds__(256)
void gemm_qk(const float* __restrict__ query, const float* __restrict__ key,
             const u16* __restrict__ Wqh, const u16* __restrict__ Wkh,
             const float* __restrict__ bq, const float* __restrict__ bk,
             u16* __restrict__ Qhi, u16* __restrict__ Khi) {
    __shared__ u16 sA[128 * 40];
    __shared__ u16 sB[128 * 40];

    const int t = threadIdx.x;
    const int lane = t & 63;
    const int w = t >> 6;
    const int wm = w >> 1, wn = w & 1;
    const int srow = t >> 1;
    const int sc = (t & 1) * 16;

    const int bid = blockIdx.x;
    const int p = bid % 96;          // row-panel: fixes XCD
    const int col = bid / 96;        // 0..7
    const int isK = p >= 32;
    const int rowBase = (isK ? p - 32 : p) * 128;
    const int colBase = col * 128;
    const float* Af = isK ? key : query;
    const u16* Wu = isK ? Wkh : Wqh;
    const float* bias = isK ? bk : bq;
    const float scale = isK ? 1.0f : PSC;
    const int bshift = isK ? 11 : 10;
    u16* Yout = isK ? Khi : Qhi;

    f32x4 acc[4][4];
#pragma unroll
    for (int i = 0; i < 4; ++i)
#pragma unroll
        for (int j = 0; j < 4; ++j) acc[i][j] = (f32x4){0.f, 0.f, 0.f, 0.f};

    float ax0[16], ax1[16];
    u16x8 wh00, wh01, wh10, wh11;

    QK_LOAD(0, 0)
    QK_LOAD(1, 32)

    for (int k0 = 0; k0 < 1024; k0 += 64) {
        __syncthreads();
        QK_WRITE(0)
        __syncthreads();
        if (k0 + 64 < 1024) QK_LOAD(0, k0 + 64)
        GEMM_COMPUTE()
        __syncthreads();
        QK_WRITE(1)
        __syncthreads();
        if (k0 + 96 < 1024) QK_LOAD(1, k0 + 96)
        GEMM_COMPUTE()
    }

#pragma unroll
    for (int mi = 0; mi < 4; ++mi)
#pragma unroll
        for (int ni = 0; ni < 4; ++ni)
#pragma unroll
            for (int rr = 0; rr < 4; ++rr) {
                int mg = rowBase + wm * 64 + mi * 16 + (lane >> 4) * 4 + rr;
                int ng = colBase + wn * 64 + ni * 16 + (lane & 15);
                float y = (acc[mi][ni][rr] + bias[ng]) * scale;
                int bb = mg >> bshift, s = mg & ((1 << bshift) - 1);
                size_t idx = ((((size_t)(bb * 16 + (ng >> 6))) << bshift) + s) * 64 + (ng & 63);
                Yout[idx] = f2bf(y);
            }
}

// ---------------------------------------------------------------------------
// V-projection: VTh = Wvh @ value^T + bv[row], V^T head-major out.
// (Natural order already keeps each value col-panel on one XCD.)
// ---------------------------------------------------------------------------
__global__ __launch_bounds__(256)
void gemm_vproj(const u16* __restrict__ Au, const float* __restrict__ Wf,
                const float* __restrict__ bias, u16* __restrict__ VTh) {
    __shared__ u16 sA[128 * 40];
    __shared__ u16 sB[128 * 40];

    const int t = threadIdx.x;
    const int lane = t & 63;
    const int w = t >> 6;
    const int wm = w >> 1, wn = w & 1;
    const int rowBase = blockIdx.y * 128;
    const int colBase = blockIdx.x * 128;
    const int srow = t >> 1;
    const int sc = (t & 1) * 16;

    f32x4 acc[4][4];
#pragma unroll
    for (int i = 0; i < 4; ++i)
#pragma unroll
        for (int j = 0; j < 4; ++j) acc[i][j] = (f32x4){0.f, 0.f, 0.f, 0.f};

    u16x8 au00, au01, au10, au11;
    float bx0[16], bx1[16];

#define VP_LOAD(S, kk) { \
    au##S##0 = *(const u16x8*)&Au[(size_t)(rowBase + srow) * 1024 + (kk) + sc]; \
    au##S##1 = *(const u16x8*)&Au[(size_t)(rowBase + srow) * 1024 + (kk) + sc + 8]; \
    _Pragma("unroll") for (int j = 0; j < 4; ++j) \
        *(float4*)&bx##S[j * 4] = *(const float4*)&Wf[(size_t)(colBase + srow) * 1024 + (kk) + sc + j * 4]; }
#define VP_WRITE(S) { \
    *(u16x8*)&sA[srow * 40 + sc] = au##S##0; \
    *(u16x8*)&sA[srow * 40 + sc + 8] = au##S##1; \
    u16x8 b0, b1; \
    _Pragma("unroll") for (int j = 0; j < 8; ++j) { \
        b0[j] = f2bf(bx##S[j]); b1[j] = f2bf(bx##S[j + 8]); } \
    *(u16x8*)&sB[srow * 40 + sc] = b0; \
    *(u16x8*)&sB[srow * 40 + sc + 8] = b1; }

    VP_LOAD(0, 0)
    VP_LOAD(1, 32)

    for (int k0 = 0; k0 < 1024; k0 += 64) {
        __syncthreads();
        VP_WRITE(0)
        __syncthreads();
        if (k0 + 64 < 1024) VP_LOAD(0, k0 + 64)
        GEMM_COMPUTE()
        __syncthreads();
        VP_WRITE(1)
        __syncthreads();
        if (k0 + 96 < 1024) VP_LOAD(1, k0 + 96)
        GEMM_COMPUTE()
    }

#pragma unroll
    for (int mi = 0; mi < 4; ++mi)
#pragma unroll
        for (int ni = 0; ni < 4; ++ni)
#pragma unroll
            for (int rr = 0; rr < 4; ++rr) {
                int mg = rowBase + wm * 64 + mi * 16 + (lane >> 4) * 4 + rr;
                int ng = colBase + wn * 64 + ni * 16 + (lane & 15);
                float y = acc[mi][ni][rr] + bias[mg];
                size_t idx = ((size_t)((ng >> 11) * 16 + (mg >> 6)) * 64 + (mg & 63)) * 2048 + (ng & 2047);
                VTh[idx] = f2bf(y);
            }
}

// ---------------------------------------------------------------------------
// O-projection with XCD remap: p = bid % 32 (row-panel -> one XCD), col = bid/32.
// ---------------------------------------------------------------------------
__global__ __launch_bounds__(256)
void gemm_oproj(const u16* __restrict__ Au, const u16* __restrict__ Wu,
                const float* __restrict__ bias, float* __restrict__ Y0p) {
    __shared__ u16 sA[128 * 40];
    __shared__ u16 sB[128 * 40];

    const int t = threadIdx.x;
    const int lane = t & 63;
    const int w = t >> 6;
    const int wm = w >> 1, wn = w & 1;
    const int p = blockIdx.x % 32;
    const int rowBase = p * 128;
    const int colBase = (blockIdx.x / 32) * 128;
    const int srow = t >> 1;
    const int sc = (t & 1) * 16;

    f32x4 acc[4][4];
#pragma unroll
    for (int i = 0; i < 4; ++i)
#pragma unroll
        for (int j = 0; j < 4; ++j) acc[i][j] = (f32x4){0.f, 0.f, 0.f, 0.f};

    u16x8 au00, au01, au10, au11;
    u16x8 wh00, wh01, wh10, wh11;

#define OP_LOAD(S, kk) { \
    au##S##0 = *(const u16x8*)&Au[(size_t)(rowBase + srow) * 1024 + (kk) + sc]; \
    au##S##1 = *(const u16x8*)&Au[(size_t)(rowBase + srow) * 1024 + (kk) + sc + 8]; \
    wh##S##0 = *(const u16x8*)&Wu[(size_t)(colBase + srow) * 1024 + (kk) + sc]; \
    wh##S##1 = *(const u16x8*)&Wu[(size_t)(colBase + srow) * 1024 + (kk) + sc + 8]; }
#define OP_WRITE(S) { \
    *(u16x8*)&sA[srow * 40 + sc] = au##S##0; \
    *(u16x8*)&sA[srow * 40 + sc + 8] = au##S##1; \
    *(u16x8*)&sB[srow * 40 + sc] = wh##S##0; \
    *(u16x8*)&sB[srow * 40 + sc + 8] = wh##S##1; }

    OP_LOAD(0, 0)
    OP_LOAD(1, 32)

    for (int k0 = 0; k0 < 1024; k0 += 64) {
        __syncthreads();
        OP_WRITE(0)
        __syncthreads();
        if (k0 + 64 < 1024) OP_LOAD(0, k0 + 64)
        GEMM_COMPUTE()
        __syncthreads();
        OP_WRITE(1)
        __syncthreads();
        if (k0 + 96 < 1024) OP_LOAD(1, k0 + 96)
        GEMM_COMPUTE()
    }

#pragma unroll
    for (int mi = 0; mi < 4; ++mi)
#pragma unroll
        for (int ni = 0; ni < 4; ++ni)
#pragma unroll
            for (int rr = 0; rr < 4; ++rr) {
                int mg = rowBase + wm * 64 + mi * 16 + (lane >> 4) * 4 + rr;
                int ng = colBase + wn * 64 + ni * 16 + (lane & 15);
                Y0p[(size_t)mg * 1024 + ng] = acc[mi][ni][rr] + bias[ng];
            }
}

// ---------------------------------------------------------------------------
// Pass 1: attended output + denominators (unchanged from r17/r19).
// ---------------------------------------------------------------------------
__global__ __launch_bounds__(512, 4)
void attn_O(const u16* __restrict__ Qhi, const u16* __restrict__ Khi,
            const u16* __restrict__ VT, u16* __restrict__ Att,
            float* __restrict__ llog) {
    __shared__ char lds[49152];
    float* sOf = (float*)lds;
    float* sL2t = (float*)(lds + 35840);
    float* sL2f = (float*)(lds + 36864);

    const int t = threadIdx.x;
    const int w = t >> 6, lane = t & 63;
    const int g = lane >> 4, c16 = lane & 15;
    const int qt = blockIdx.x >> 6;
    const int g6 = blockIdx.x & 63;
    const int b = g6 >> 4, h = g6 & 15;
    const int qbase = qt * 128;
    const int wq = w >> 1, wk = w & 1;
    const int kswz = (g ^ (c16 & 7)) << 4;
    const int vsw0 = (((wk * 4 + 0 + (g >> 1)) ^ (c16 & 7)) << 4) | ((g & 1) << 3);
    const int vsw1 = (((wk * 4 + 2 + (g >> 1)) ^ (c16 & 7)) << 4) | ((g & 1) << 3);

    const char* Kh_g = (const char*)(Khi + (size_t)(b * 16 + h) * SKL * 64);
    const char* V_g  = (const char*)(VT + (size_t)(b * 16 + h) * 64 * SKL);

    s16x8 qh[2][2];
    const size_t qrowbase = (size_t)(b * 16 + h) * SQL + qbase;
#pragma unroll
    for (int qf = 0; qf < 2; ++qf) {
        size_t qo = (qrowbase + wq * 32 + qf * 16 + c16) * 64 + g * 8;
        qh[qf][0] = *(const s16x8*)&Qhi[qo];
        qh[qf][1] = *(const s16x8*)&Qhi[qo + 32];
    }

    stage8k(Kh_g, 128, lds, w, lane);
    stage8k(V_g, 4096, lds + 24576, w, lane);
    stage8k(Kh_g + 8192, 128, lds + 8192, w, lane);
    stage8k(V_g + 128, 4096, lds + 24576 + 8192, w, lane);

    const s16x4 onesf = {(short)0x3F80, (short)0x3F80, (short)0x3F80, (short)0x3F80};
    f32x4 oacc[2][4];
    f32x4 lacc[2];
    float lsum[2] = {0.f, 0.f};
#pragma unroll
    for (int qf = 0; qf < 2; ++qf) {
        lacc[qf] = (f32x4){0.f, 0.f, 0.f, 0.f};
#pragma unroll
        for (int i = 0; i < 4; ++i) oacc[qf][i] = (f32x4){0.f, 0.f, 0.f, 0.f};
    }

    int cur = 0;
    for (int c = 0; c < 32; ++c) {
        if (c < 31) { asm volatile("s_waitcnt vmcnt(2)" ::: "memory"); }
        else        { asm volatile("s_waitcnt vmcnt(0)" ::: "memory"); }
        SBAR();
        if (c + 2 < 32) {
            int nb = cur + 2; if (nb >= 3) nb -= 3;
            stage8k(Kh_g + (size_t)(c + 2) * 8192, 128, lds + nb * 8192, w, lane);
            stage8k(V_g + (size_t)(c + 2) * 128, 4096, lds + 24576 + nb * 8192, w, lane);
        }
        char* curK = lds + cur * 8192;
        char* curV = lds + 24576 + cur * 8192;
#pragma unroll
        for (int kf = 0; kf < 2; ++kf) {
            int kb = (wk * 32 + kf * 16 + c16) * 128 + kswz;
            s16x8 kh0 = *(const s16x8*)(curK + kb);
            s16x8 kh1 = *(const s16x8*)(curK + (kb ^ 64));
            s16x4 pb[2];
#pragma unroll
            for (int qf = 0; qf < 2; ++qf) {
                f32x4 s = {0.f, 0.f, 0.f, 0.f};
                s = mfma16(kh0, qh[qf][0], s);
                s = mfma16(kh1, qh[qf][1], s);
                float e0 = exp2f(s[0]);
                float e1 = exp2f(s[1]);
                float e2 = exp2f(s[2]);
                float e3 = exp2f(s[3]);
                lsum[qf] += (e0 + e1) + (e2 + e3);
                u32x2 pu = {permpack(e0, e1), permpack(e2, e3)};
                pb[qf] = __builtin_bit_cast(s16x4, pu);
                lacc[qf] = mfma16k16(onesf, pb[qf], lacc[qf]);
            }
            int vs = kf ? vsw1 : vsw0;
#pragma unroll
            for (int df = 0; df < 4; ++df) {
                s16x4 vf = *(const s16x4*)(curV + (df * 16 + c16) * 128 + vs);
                oacc[0][df] = mfma16k16(vf, pb[0], oacc[0][df]);
                oacc[1][df] = mfma16k16(vf, pb[1], oacc[1][df]);
            }
        }
        ++cur; if (cur == 3) cur = 0;
    }

#pragma unroll
    for (int qf = 0; qf < 2; ++qf) {
        lsum[qf] += __shfl_xor(lsum[qf], 16, 64);
        lsum[qf] += __shfl_xor(lsum[qf], 32, 64);
    }
    __syncthreads();
#pragma unroll
    for (int qf = 0; qf < 2; ++qf)
        if (g == 0) {
            sL2t[wk * 128 + wq * 32 + qf * 16 + c16] = lacc[qf][0];
            sL2f[wk * 128 + wq * 32 + qf * 16 + c16] = lsum[qf];
        }

#pragma unroll
    for (int half = 0; half < 2; ++half) {
        if (half) __syncthreads();
        if ((wq >> 1) == half) {
            int qlocal = (wq & 1) * 32 + c16;
#pragma unroll
            for (int qf = 0; qf < 2; ++qf)
#pragma unroll
                for (int df = 0; df < 4; ++df)
#pragma unroll
                    for (int r = 0; r < 4; ++r)
                        sOf[wk * 4352 + (df * 16 + g * 4 + r) * 68 + qlocal + qf * 16] =
                            oacc[qf][df][r];
        }
        __syncthreads();
        {
            int q = t >> 3, dg = t & 7;
            float lt = sL2t[half * 64 + q] + sL2t[128 + half * 64 + q];
            float linv = 1.f / lt;
            u16x8 ov;
#pragma unroll
            for (int i = 0; i < 8; ++i) {
                int d = dg * 8 + i;
                ov[i] = f2bf((sOf[d * 68 + q] + sOf[4352 + d * 68 + q]) * linv);
            }
            *(u16x8*)&Att[(size_t)(b * SQL + qbase + half * 64 + q) * EMBED + h * 64 + dg * 8] = ov;
            if (dg == 0) {
                float lf = sL2f[half * 64 + q] + sL2f[128 + half * 64 + q];
                llog[(size_t)(b * 16 + h) * SQL + qbase + half * 64 + q] = log2f(lf);
            }
        }
    }
}

// ---------------------------------------------------------------------------
// Pass 2: mean_attn (unchanged from r17/r19).
// ---------------------------------------------------------------------------
__global__ __launch_bounds__(512, 4)
void attn_mean(const u16* __restrict__ Qhi, const u16* __restrict__ Khi,
               const float* __restrict__ llog, float* __restrict__ meanOut) {
    __shared__ char lds[81920];   // Q dbuf 2x16K @0; K tbuf 3x16K @32768

    const int t = threadIdx.x;
    const int w = t >> 6, lane = t & 63;
    const int g = lane >> 4, c16 = lane & 15;
    const int qt = blockIdx.x >> 6;
    const int low = blockIdx.x & 63;
    const int b = low >> 4, ks = low & 15;
    const int qbase = qt * 128;
    const int kbase = ks * 128;
    const int wq = w >> 1, wk = w & 1;
    const int kswz = (g ^ (c16 & 7)) << 4;

    const size_t QH_STRIDE = (size_t)SQL * 128;
    const size_t KH_STRIDE = (size_t)SKL * 128;
    const char* Qh_b = (const char*)(Qhi + ((size_t)(b * 16) * SQL + qbase) * 64);
    const char* Kh_b = (const char*)(Khi + ((size_t)(b * 16) * SKL + kbase) * 64);
    const float* ll_b = llog + (size_t)(b * 16) * SQL + qbase;

    f32x4 ma[2][4];
#pragma unroll
    for (int qf = 0; qf < 2; ++qf)
#pragma unroll
        for (int i = 0; i < 4; ++i) ma[qf][i] = (f32x4){0.f, 0.f, 0.f, 0.f};

    stage8k(Qh_b, 128, lds, w, lane);
    stage8k(Qh_b + 8192, 128, lds + 8192, w, lane);
    float lbA0 = ll_b[wq * 32 + c16];
    float lbA1 = ll_b[wq * 32 + 16 + c16];
    stage8k(Kh_b, 128, lds + 32768, w, lane);
    stage8k(Kh_b + 8192, 128, lds + 32768 + 8192, w, lane);
    stage8k(Qh_b + QH_STRIDE, 128, lds + 16384, w, lane);
    stage8k(Qh_b + QH_STRIDE + 8192, 128, lds + 16384 + 8192, w, lane);
    float lbB0 = ll_b[SQL + wq * 32 + c16];
    float lbB1 = ll_b[SQL + wq * 32 + 16 + c16];
    stage8k(Kh_b + KH_STRIDE, 128, lds + 32768 + 16384, w, lane);
    stage8k(Kh_b + KH_STRIDE + 8192, 128, lds + 32768 + 16384 + 8192, w, lane);

    int curK = 0;
    for (int h = 0; h < 16; ++h) {
        if (h < 15) { asm volatile("s_waitcnt vmcnt(4)" ::: "memory"); }
        else        { asm volatile("s_waitcnt vmcnt(0)" ::: "memory"); }
        SBAR();

        const char* sQ = lds + (h & 1) * 16384;
        s16x8 qa0, qa1, qc0, qc1;
        {
            int qb0 = (wq * 32 + c16) * 128 + kswz;
            qa0 = *(const s16x8*)(sQ + qb0);
            qa1 = *(const s16x8*)(sQ + (qb0 ^ 64));
            int qb1 = (wq * 32 + 16 + c16) * 128 + kswz;
            qc0 = *(const s16x8*)(sQ + qb1);
            qc1 = *(const s16x8*)(sQ + (qb1 ^ 64));
        }
        asm volatile("s_waitcnt lgkmcnt(0)" ::: "memory");
        SBAR();

        float lb0 = lbA0, lb1 = lbA1;
        lbA0 = lbB0; lbA1 = lbB1;

        if (h + 2 < 16) {
            const char* Qg = Qh_b + (size_t)(h + 2) * QH_STRIDE;
            char* qdst = lds + (h & 1) * 16384;
            stage8k(Qg, 128, qdst, w, lane);
            stage8k(Qg + 8192, 128, qdst + 8192, w, lane);
            lbB0 = ll_b[(size_t)(h + 2) * SQL + wq * 32 + c16];
            lbB1 = ll_b[(size_t)(h + 2) * SQL + wq * 32 + 16 + c16];
            const char* Kg = Kh_b + (size_t)(h + 2) * KH_STRIDE;
            int nb = curK + 2; if (nb >= 3) nb -= 3;
            char* kdst = lds + 32768 + nb * 16384;
            stage8k(Kg, 128, kdst, w, lane);
            stage8k(Kg + 8192, 128, kdst + 8192, w, lane);
        }

        const char* sK = lds + 32768 + curK * 16384;
#pragma unroll
        for (int kf = 0; kf < 4; ++kf) {
            int kb = (kf * 32 + wk * 16 + c16) * 128 + kswz;
            s16x8 kh0 = *(const s16x8*)(sK + kb);
            s16x8 kh1 = *(const s16x8*)(sK + (kb ^ 64));
            {
                f32x4 s = {0.f, 0.f, 0.f, 0.f};
                s = mfma16(kh0, qa0, s);
                s = mfma16(kh1, qa1, s);
                ma[0][kf][0] += exp2f(s[0] - lb0);
                ma[0][kf][1] += exp2f(s[1] - lb0);
                ma[0][kf][2] += exp2f(s[2] - lb0);
                ma[0][kf][3] += exp2f(s[3] - lb0);
            }
            {
                f32x4 s = {0.f, 0.f, 0.f, 0.f};
                s = mfma16(kh0, qc0, s);
                s = mfma16(kh1, qc1, s);
                ma[1][kf][0] += exp2f(s[0] - lb1);
                ma[1][kf][1] += exp2f(s[1] - lb1);
                ma[1][kf][2] += exp2f(s[2] - lb1);
                ma[1][kf][3] += exp2f(s[3] - lb1);
            }
        }
        ++curK; if (curK == 3) curK = 0;
    }

    const float s16c = 1.f / 16.f;
#pragma unroll
    for (int qf = 0; qf < 2; ++qf)
#pragma unroll
        for (int kf = 0; kf < 4; ++kf) {
            f32x4 m = ma[qf][kf];
            m[0] *= s16c; m[1] *= s16c; m[2] *= s16c; m[3] *= s16c;
            *(f32x4*)&meanOut[(size_t)(b * SQL + qbase + wq * 32 + qf * 16 + c16) * SKL +
                              kbase + kf * 32 + wk * 16 + g * 4] = m;
        }
}

// ---------------------------------------------------------------------------
extern "C" void kernel_launch(void* const* d_in, const int* in_sizes, int n_in,
                              void* d_out, int out_size, void* d_ws, size_t ws_size,
                              hipStream_t stream) {
    const float* query = (const float*)d_in[0];
    const float* key   = (const float*)d_in[1];
    const float* value = (const float*)d_in[2];
    const float* Wq = (const float*)d_in[3];
    const float* bq = (const float*)d_in[4];
    const float* Wk = (const float*)d_in[5];
    const float* bk = (const float*)d_in[6];
    const float* Wv = (const float*)d_in[7];
    const float* bv = (const float*)d_in[8];
    const float* Wo = (const float*)d_in[9];
    const float* bo = (const float*)d_in[10];

    float* out = (float*)d_out;                         // [4,1024,1024] f32
    float* meanOut = out + (size_t)BATCH * SQL * EMBED; // [4,1024,2048] f32

    u16* Qhi = (u16*)d_ws;                              // head-major [b][h][q][64], pre-scaled by PSC
    u16* Khi = Qhi + (size_t)4096 * 1024;               // [b][h][k][64]
    u16* VTh = Khi + (size_t)8192 * 1024;               // [b][h][d][2048]
    u16* Att = VTh + (size_t)8192 * 1024;               // [4096][1024] bf16
    float* llog = (float*)(Att + (size_t)4096 * 1024);  // [b*16+h][q]
    u16* Wqh = (u16*)(llog + 64 * 1024);                // bf16 weight planes
    u16* Wkh = Wqh + (size_t)1024 * 1024;
    u16* Wvh = Wkh + (size_t)1024 * 1024;
    u16* Woh = Wvh + (size_t)1024 * 1024;

    cvt_w<<<dim3(2048), 256, 0, stream>>>(Wq, Wk, Wv, Wo, Wqh, Wkh, Wvh, Woh);

    gemm_qk<<<dim3(768), 256, 0, stream>>>(query, key, Wqh, Wkh, bq, bk, Qhi, Khi);
    gemm_vproj<<<dim3(64, 8), 256, 0, stream>>>(Wvh, value, bv, VTh);

    attn_O<<<dim3(512), dim3(512), 0, stream>>>(Qhi, Khi, VTh, Att, llog);
    attn_mean<<<dim3(512), dim3(512), 0, stream>>>(Qhi, Khi, llog, meanOut);

    gemm_oproj<<<dim3(256), 256, 0, stream>>>(Att, Woh, bo, out);
}